// Round 8
// baseline (487.602 us; speedup 1.0000x reference)
//
#include <hip/hip_runtime.h>
#include <math.h>

#define N 1024
#define BATCH 16
#define CH 3
#define BC 48
#define GROUPS 4
#define GBC 12                               // images per group
#define OUTHW 224
#define KSCALE (1024.0f / 224.0f)
#define SCALE  (224.0f / 1024.0f)
#define SLABF  2097152                       // floats per A slab (8 MB)
#define ABYTES ((size_t)BC * N * N * 8)      // legacy offset for twg (ws is >= this)
#define SLOTOFF 1802240                      // slots: slab-0 tail (untouched by A writes)
#define T1BASE ((size_t)GBC * SLABF)         // T1 region: after 12-slab A scratch (96 MB)
#define T1SZ   (OUTHW * N)                   // 229376 floats per bc
#define WBAR() __builtin_amdgcn_wave_barrier()

// (ar,ai)*(br,bi) -> (dr,di); safe when d aliases a
#define CMUL(dr, di, ar, ai, br, bi) do {                         \
    float _r = (ar) * (br) - (ai) * (bi);                         \
    float _i = (ar) * (bi) + (ai) * (br);                         \
    (dr) = _r; (di) = _i; } while (0)

// forward DFT-4
#define RADIX4(ar,ai,br,bi,cr,ci,dr,di, o0r,o0i,o1r,o1i,o2r,o2i,o3r,o3i) do { \
    float u0r=(ar)+(cr), u0i=(ai)+(ci);                           \
    float u1r=(ar)-(cr), u1i=(ai)-(ci);                           \
    float u2r=(br)+(dr), u2i=(bi)+(di);                           \
    float u3r=(bi)-(di), u3i=(dr)-(br);                           \
    (o0r)=u0r+u2r; (o0i)=u0i+u2i;                                 \
    (o1r)=u1r+u3r; (o1i)=u1i+u3i;                                 \
    (o2r)=u0r-u2r; (o2i)=u0i-u2i;                                 \
    (o3r)=u1r-u3r; (o3i)=u1i-u3i; } while (0)

// In-register natural-order 16-pt forward DFT (Stockham radix-4 x radix-4).
__device__ __forceinline__ void dft16(float* xr, float* xi) {
  const float W16R[4][4] = {
    {1.f, 1.f, 1.f, 1.f},
    {1.f,  0.9238795325f,  0.7071067812f,  0.3826834324f},
    {1.f,  0.7071067812f,  0.0f,          -0.7071067812f},
    {1.f,  0.3826834324f, -0.7071067812f, -0.9238795325f}};
  const float W16I[4][4] = {
    {0.f, 0.f, 0.f, 0.f},
    {0.f, -0.3826834324f, -0.7071067812f, -0.9238795325f},
    {0.f, -0.7071067812f, -1.0f,          -0.7071067812f},
    {0.f, -0.9238795325f, -0.7071067812f,  0.3826834324f}};
  float tr[16], ti[16];
#pragma unroll
  for (int j = 0; j < 4; ++j) {
    RADIX4(xr[j],xi[j], xr[j+4],xi[j+4], xr[j+8],xi[j+8], xr[j+12],xi[j+12],
           tr[4*j],ti[4*j], tr[4*j+1],ti[4*j+1], tr[4*j+2],ti[4*j+2], tr[4*j+3],ti[4*j+3]);
  }
#pragma unroll
  for (int j = 0; j < 4; ++j) {
    float ar[4], ai_[4];
#pragma unroll
    for (int k = 0; k < 4; ++k) {
      if (j == 0 || k == 0) { ar[k] = tr[j+4*k]; ai_[k] = ti[j+4*k]; }
      else CMUL(ar[k], ai_[k], tr[j+4*k], ti[j+4*k], W16R[j][k], W16I[j][k]);
    }
    RADIX4(ar[0],ai_[0], ar[1],ai_[1], ar[2],ai_[2], ar[3],ai_[3],
           xr[j],xi[j], xr[j+4],xi[j+4], xr[j+8],xi[j+8], xr[j+12],xi[j+12]);
  }
}

__device__ __forceinline__ void stage2(float* xr, float* xi,
                                       const float2* __restrict__ twg, int j2) {
#pragma unroll
  for (int k = 1; k < 16; ++k) {       // twiddle W256^{j2*k}
    float2 w = twg[4 * j2 * k];
    CMUL(xr[k], xi[k], xr[k], xi[k], w.x, w.y);
  }
  dft16(xr, xi);
}

// 1-buffer wave FFT (R4-proven): sequential re/im round-trips through ONE
// 1088-float buffer (in-order DS pipe). Ex2 gather lands at slots xr[m+4k],
// making stage 3 an exact in-place butterfly.
__device__ __forceinline__ void wave_fft1024_1buf(float* xr, float* xi,
                                                  float* wb,
                                                  const float2* __restrict__ twg,
                                                  int l) {
  const int base2 = l + (l >> 4);
  const int j2 = l & 15;
  const int ob = 272 * (l >> 4) + j2;
  dft16(xr, xi);                       // stage 1 (Ns=1)
#pragma unroll
  for (int k = 0; k < 16; ++k) wb[17*l + k] = xr[k];
  WBAR();
#pragma unroll
  for (int k = 0; k < 16; ++k) xr[k] = wb[base2 + 68*k];
  WBAR();
#pragma unroll
  for (int k = 0; k < 16; ++k) wb[17*l + k] = xi[k];
  WBAR();
#pragma unroll
  for (int k = 0; k < 16; ++k) xi[k] = wb[base2 + 68*k];
  WBAR();
  stage2(xr, xi, twg, j2);             // stage 2 (Ns=16)
#pragma unroll
  for (int k = 0; k < 16; ++k) wb[ob + 17*k] = xr[k];
  WBAR();
#pragma unroll
  for (int m = 0; m < 4; ++m)
#pragma unroll
    for (int k = 0; k < 4; ++k) xr[m + 4*k] = wb[base2 + 68*m + 272*k];
  WBAR();
#pragma unroll
  for (int k = 0; k < 16; ++k) wb[ob + 17*k] = xi[k];
  WBAR();
#pragma unroll
  for (int m = 0; m < 4; ++m)
#pragma unroll
    for (int k = 0; k < 4; ++k) xi[m + 4*k] = wb[base2 + 68*m + 272*k];
  WBAR();
#pragma unroll
  for (int m = 0; m < 4; ++m) {        // stage 3 (Ns=256, radix-4), in-place
    float ar[4], ai_[4];
#pragma unroll
    for (int k = 0; k < 4; ++k) { ar[k] = xr[m + 4*k]; ai_[k] = xi[m + 4*k]; }
    const int j = l + 64*m;
#pragma unroll
    for (int k = 1; k < 4; ++k) {
      float2 w = twg[j * k];
      CMUL(ar[k], ai_[k], ar[k], ai_[k], w.x, w.y);
    }
    RADIX4(ar[0],ai_[0], ar[1],ai_[1], ar[2],ai_[2], ar[3],ai_[3],
           xr[m],xi[m], xr[m+4],xi[m+4], xr[m+8],xi[m+8], xr[m+12],xi[m+12]);
  }
}

__global__ void k_init(float2* __restrict__ tw, int* __restrict__ slots) {
  int g = blockIdx.x * 256 + threadIdx.x;   // 0..2047
  if (g < 1024) {
    float ang = -6.283185307179586f * ((float)g / 1024.0f);
    float s, c;
    sincosf(ang, &s, &c);
    tw[g] = make_float2(c, s);
    slots[g] = 0x7F800000;                  // +inf (min slots, 16 b x 64 slices)
  } else {
    slots[g] = 0;                           // 0 (max slots; spec >= 0)
  }
}

// Pass 1 (R7 kernel, chunked): 8 waves/block, 16 rows, 1-buffer FFT, Hermitian
// unpack + transposed staging in two v-halves. Operates on a 12-image group:
// `in` is pre-offset to the group's first image; A is the reused 12-slab
// scratch (L3-resident — the point of R8).
__global__ __launch_bounds__(512, 6) void k_rowfft(const float* __restrict__ in,
                                                   float2* __restrict__ A,
                                                   const float2* __restrict__ twg) {
  __shared__ float lds[8704];          // 8 waves x 1088; overlaid: stg [16][260] x2
  const int t  = threadIdx.x;
  const int w  = t >> 6;               // 0..7
  const int l  = t & 63;
  const int bcl = blockIdx.x >> 6;     // local image 0..11
  const int h0b = (blockIdx.x & 63) << 4;   // 16 rows per block
  const int r0  = h0b + 2 * w;
  float* wb = lds + w * 1088;
  const float* row0 = in + ((size_t)bcl << 20) + ((size_t)r0 << 10);
  const float* row1 = row0 + N;
  float xr[16], xi[16];
  const float sgn = (l & 1) ? -1.0f : 1.0f;   // fftshift sign (-1)^h
#pragma unroll
  for (int k = 0; k < 16; ++k) {
    xr[k] =  sgn * row0[l + 64*k];
    xi[k] = -sgn * row1[l + 64*k];
  }
  wave_fft1024_1buf(xr, xi, wb, twg, l);
  float* stre = lds;                   // [16][260]
  float* stim = lds + 4160;            // [16][260]
  const int rr = t & 15, v0 = t >> 4;  // 128B transposed chunk coords
  float2* Abc = A + ((size_t)bcl << 20);
#pragma unroll
  for (int h = 0; h < 2; ++h) {
    const int slo = (h == 0) ? 0 : 4;
    const int cnt = (h == 0) ? 4 : 5;
    float par[5], pai[5], pbr[5], pbi[5];
    __syncthreads();
#pragma unroll
    for (int s = 0; s < 16; ++s) wb[l + 64*s] = xr[s];
    WBAR();
#pragma unroll
    for (int u = 0; u < 5; ++u) {
      if (u < cnt) {
        int s = slo + u;
        int i = l + 64*s;
        if (i <= 512) {
          float qr = wb[(N - i) & (N - 1)];
          par[u] = 0.5f * (xr[s] + qr);
          pbi[u] = 0.5f * (qr - xr[s]);
        }
      }
    }
    WBAR();
#pragma unroll
    for (int s = 0; s < 16; ++s) wb[l + 64*s] = xi[s];
    WBAR();
#pragma unroll
    for (int u = 0; u < 5; ++u) {
      if (u < cnt) {
        int s = slo + u;
        int i = l + 64*s;
        if (i <= 512) {
          float qi = wb[(N - i) & (N - 1)];
          pai[u] = 0.5f * (xi[s] - qi);
          pbr[u] = 0.5f * (xi[s] + qi);
        }
      }
    }
    __syncthreads();
#pragma unroll
    for (int u = 0; u < 5; ++u) {
      if (u < cnt) {
        int s = slo + u;
        int i = l + 64*s;
        if (i <= 512) {
          int c = i - 256 * h;
          stre[(2*w)     * 260 + c] = par[u]; stim[(2*w)     * 260 + c] = pai[u];
          stre[(2*w + 1) * 260 + c] = pbr[u]; stim[(2*w + 1) * 260 + c] = pbi[u];
        }
      }
    }
    __syncthreads();
#pragma unroll
    for (int i2 = 0; i2 < 9; ++i2) {
      if (i2 < 8 + h) {
        int v = 256 * h + v0 + 32 * i2;
        if (v <= 512) {
          int c = v - 256 * h;
          Abc[(size_t)v * N + h0b + rr] =
              make_float2(stre[rr*260 + c], stim[rr*260 + c]);
        }
      }
    }
  }
}

// Pass 2 (R4 kernel, chunked): fused column FFT + spec + sliced minmax atomics
// + 10-tap fused resize (column sx, mirror N-sx). bc0 = group's first image.
__global__ __launch_bounds__(256, 8) void k_colfft(const float2* __restrict__ A,
                                                   float* __restrict__ WSf,
                                                   int* __restrict__ slots,
                                                   const float2* __restrict__ twg,
                                                   int bc0) {
  __shared__ float lds[4352];          // 4 waves x 1088
  const int t  = threadIdx.x;
  const int w  = t >> 6;
  const int l  = t & 63;
  const int gw = blockIdx.x * 4 + w;   // 0..GBC*513-1 exactly
  const int bcl = gw / 513;
  const int sx = gw - bcl * 513;
  const int b  = (bc0 + bcl) / CH;
  float* wb = lds + w * 1088;
  const float2* src = A + ((size_t)bcl << 20) + ((size_t)sx << 10);
  float xr[16], xi[16];
#pragma unroll
  for (int k = 0; k < 16; ++k) { float2 v = src[l + 64*k]; xr[k] = v.x; xi[k] = v.y; }
  wave_fft1024_1buf(xr, xi, wb, twg, l);
  float lmin = 3.4e38f, lmax = 0.0f;
#pragma unroll
  for (int s = 0; s < 16; ++s) {
    float sp = __logf(1.0f + sqrtf(xr[s]*xr[s] + xi[s]*xi[s]));
    wb[l + 64*s] = sp;                 // spec plain-indexed in own buffer
    lmin = fminf(lmin, sp); lmax = fmaxf(lmax, sp);
  }
#pragma unroll
  for (int off = 32; off; off >>= 1) {
    lmin = fminf(lmin, __shfl_xor(lmin, off));
    lmax = fmaxf(lmax, __shfl_xor(lmax, off));
  }
  if (l == 0) {                        // spread over 64 slices/image
    atomicMin(&slots[b * 64 + (sx & 63)],        __float_as_int(lmin));
    atomicMax(&slots[1024 + b * 64 + (sx & 63)], __float_as_int(lmax));
  }
  WBAR();
  float* T1 = WSf + T1BASE + (size_t)(bc0 + bcl) * T1SZ;
  const bool mir = (sx != 0) && (sx != 512);
#pragma unroll
  for (int obk = 0; obk < 4; ++obk) {
    int oh = l + 64 * obk;
    if (oh < OUTHW) {
      float x = ((float)oh + 0.5f) * KSCALE - 0.5f;
      int jlo = (int)ceilf(x - KSCALE);           // unclamped; window < 10 taps
      float ssum = 0.0f, acc = 0.0f, accm = 0.0f;
#pragma unroll
      for (int u = 0; u < 10; ++u) {
        int j = jlo + u;
        float wgt = 1.0f - fabsf((float)j - x) * SCALE;
        wgt = fmaxf(wgt, 0.0f);
        bool valid = (j >= 0) && (j <= N - 1);
        if (!valid) wgt = 0.0f;
        int ja = valid ? j : 0;
        ssum += wgt;
        acc  += wgt * wb[ja];
        accm += wgt * wb[(N - ja) & (N - 1)];
      }
      float inv = 1.0f / ssum;
      T1[(size_t)sx * OUTHW + oh] = acc * inv;
      if (mir) T1[(size_t)(N - sx) * OUTHW + oh] = accm * inv;
    }
  }
}

// Pass 3 (R6-exact, new T1 region): contract v + normalization; direct
// coalesced T1 reads, fixed 10-tap loop, slot min/max reduction merged in.
__global__ __launch_bounds__(256) void k_resize2(const float* __restrict__ WSf,
                                                 const int* __restrict__ slots,
                                                 float* __restrict__ out) {
  __shared__ float s2[2];
  const int ow = blockIdx.x % OUTHW;
  const int bc = blockIdx.x / OUTHW;
  const int b  = bc / CH;
  const int t  = threadIdx.x;
  if (t < 64) {
    int mn = slots[b * 64 + t];
#pragma unroll
    for (int off = 32; off; off >>= 1) mn = min(mn, __shfl_xor(mn, off));
    if (t == 0) s2[0] = __int_as_float(mn);
  } else if (t < 128) {
    int mx = slots[1024 + b * 64 + (t - 64)];
#pragma unroll
    for (int off = 32; off; off >>= 1) mx = max(mx, __shfl_xor(mx, off));
    if (t == 64) s2[1] = __int_as_float(mx);
  }
  __syncthreads();
  if (t >= OUTHW) return;
  const float mn = s2[0];
  const float mx = s2[1];
  const float inv = 1.0f / (mx - mn + 1e-8f);
  const float* T1 = WSf + T1BASE + (size_t)bc * T1SZ;
  float x = ((float)ow + 0.5f) * KSCALE - 0.5f;
  int jlo = (int)ceilf(x - KSCALE);              // unclamped; window < 10 taps
  float ssum = 0.0f, acc = 0.0f;
#pragma unroll
  for (int u = 0; u < 10; ++u) {
    int j = jlo + u;
    float wv = 1.0f - fabsf((float)j - x) * SCALE;
    wv = fmaxf(wv, 0.0f);
    bool valid = (j >= 0) && (j <= N - 1);
    if (!valid) wv = 0.0f;
    int ja = valid ? j : 0;                      // row 0 always valid memory
    ssum += wv;
    acc += wv * T1[(size_t)ja * OUTHW + t];      // coalesced 896B per tap row
  }
  float v = acc / ssum;
  out[((size_t)bc * OUTHW + t) * OUTHW + ow] = (v - mn) * inv;
}

extern "C" void kernel_launch(void* const* d_in, const int* in_sizes, int n_in,
                              void* d_out, int out_size, void* d_ws, size_t ws_size,
                              hipStream_t stream) {
  const float* in = (const float*)d_in[0];
  float* out = (float*)d_out;
  float2* A = (float2*)d_ws;                   // 12-slab (96 MB) reused scratch
  float* WSf = (float*)d_ws;
  float2* twg = (float2*)((char*)d_ws + ABYTES + 128);
  int* slots = (int*)(WSf + SLOTOFF);          // slab-0 tail (A writes stop at 4.2 MB)

  k_init<<<8, 256, 0, stream>>>(twg, slots);
  for (int g = 0; g < GROUPS; ++g) {
    // group g: images bc0..bc0+11; A scratch reused -> stays L3-resident,
    // its dirty lines get overwritten in place by the next group (no HBM writeback)
    const int bc0 = g * GBC;
    k_rowfft<<<GBC * 64, 512, 0, stream>>>(in + ((size_t)bc0 << 20), A, twg);
    k_colfft<<<(GBC * 513) / 4, 256, 0, stream>>>(A, WSf, slots, twg, bc0);
  }
  k_resize2<<<BC * OUTHW, 256, 0, stream>>>(WSf, slots, out);
}

// Round 9
// 430.849 us; speedup vs baseline: 1.1317x; 1.1317x over previous
//
#include <hip/hip_runtime.h>
#include <math.h>

#define N 1024
#define BATCH 16
#define CH 3
#define BC 48
#define OUTHW 224
#define KSCALE (1024.0f / 224.0f)
#define SCALE  (224.0f / 1024.0f)
#define ABYTES ((size_t)BC * N * N * 8)      // 384 MiB workspace (48 x 8 MB slabs)
#define T1OFF  (768 * 2048)                  // float offset of T1 inside each slab
#define SLOTOFF 1802240                      // slab-0 tail: after T1 (1572864+1024*224)
#define WBAR() __builtin_amdgcn_wave_barrier()

// (ar,ai)*(br,bi) -> (dr,di); safe when d aliases a
#define CMUL(dr, di, ar, ai, br, bi) do {                         \
    float _r = (ar) * (br) - (ai) * (bi);                         \
    float _i = (ar) * (bi) + (ai) * (br);                         \
    (dr) = _r; (di) = _i; } while (0)

// forward DFT-4
#define RADIX4(ar,ai,br,bi,cr,ci,dr,di, o0r,o0i,o1r,o1i,o2r,o2i,o3r,o3i) do { \
    float u0r=(ar)+(cr), u0i=(ai)+(ci);                           \
    float u1r=(ar)-(cr), u1i=(ai)-(ci);                           \
    float u2r=(br)+(dr), u2i=(bi)+(di);                           \
    float u3r=(bi)-(di), u3i=(dr)-(br);                           \
    (o0r)=u0r+u2r; (o0i)=u0i+u2i;                                 \
    (o1r)=u1r+u3r; (o1i)=u1i+u3i;                                 \
    (o2r)=u0r-u2r; (o2i)=u0i-u2i;                                 \
    (o3r)=u1r-u3r; (o3i)=u1i-u3i; } while (0)

// In-register natural-order 16-pt forward DFT (Stockham radix-4 x radix-4).
__device__ __forceinline__ void dft16(float* xr, float* xi) {
  const float W16R[4][4] = {
    {1.f, 1.f, 1.f, 1.f},
    {1.f,  0.9238795325f,  0.7071067812f,  0.3826834324f},
    {1.f,  0.7071067812f,  0.0f,          -0.7071067812f},
    {1.f,  0.3826834324f, -0.7071067812f, -0.9238795325f}};
  const float W16I[4][4] = {
    {0.f, 0.f, 0.f, 0.f},
    {0.f, -0.3826834324f, -0.7071067812f, -0.9238795325f},
    {0.f, -0.7071067812f, -1.0f,          -0.7071067812f},
    {0.f, -0.9238795325f, -0.7071067812f,  0.3826834324f}};
  float tr[16], ti[16];
#pragma unroll
  for (int j = 0; j < 4; ++j) {
    RADIX4(xr[j],xi[j], xr[j+4],xi[j+4], xr[j+8],xi[j+8], xr[j+12],xi[j+12],
           tr[4*j],ti[4*j], tr[4*j+1],ti[4*j+1], tr[4*j+2],ti[4*j+2], tr[4*j+3],ti[4*j+3]);
  }
#pragma unroll
  for (int j = 0; j < 4; ++j) {
    float ar[4], ai_[4];
#pragma unroll
    for (int k = 0; k < 4; ++k) {
      if (j == 0 || k == 0) { ar[k] = tr[j+4*k]; ai_[k] = ti[j+4*k]; }
      else CMUL(ar[k], ai_[k], tr[j+4*k], ti[j+4*k], W16R[j][k], W16I[j][k]);
    }
    RADIX4(ar[0],ai_[0], ar[1],ai_[1], ar[2],ai_[2], ar[3],ai_[3],
           xr[j],xi[j], xr[j+4],xi[j+4], xr[j+8],xi[j+8], xr[j+12],xi[j+12]);
  }
}

__device__ __forceinline__ void stage2(float* xr, float* xi,
                                       const float2* __restrict__ twg, int j2) {
#pragma unroll
  for (int k = 1; k < 16; ++k) {       // twiddle W256^{j2*k}
    float2 w = twg[4 * j2 * k];
    CMUL(xr[k], xi[k], xr[k], xi[k], w.x, w.y);
  }
  dft16(xr, xi);
}

// 1-buffer wave FFT (R4-proven): sequential re/im round-trips through ONE
// 1088-float buffer (in-order DS pipe). Ex2 gather lands at slots xr[m+4k],
// making stage 3 an exact in-place butterfly.
__device__ __forceinline__ void wave_fft1024_1buf(float* xr, float* xi,
                                                  float* wb,
                                                  const float2* __restrict__ twg,
                                                  int l) {
  const int base2 = l + (l >> 4);
  const int j2 = l & 15;
  const int ob = 272 * (l >> 4) + j2;
  dft16(xr, xi);                       // stage 1 (Ns=1)
#pragma unroll
  for (int k = 0; k < 16; ++k) wb[17*l + k] = xr[k];
  WBAR();
#pragma unroll
  for (int k = 0; k < 16; ++k) xr[k] = wb[base2 + 68*k];
  WBAR();
#pragma unroll
  for (int k = 0; k < 16; ++k) wb[17*l + k] = xi[k];
  WBAR();
#pragma unroll
  for (int k = 0; k < 16; ++k) xi[k] = wb[base2 + 68*k];
  WBAR();
  stage2(xr, xi, twg, j2);             // stage 2 (Ns=16)
#pragma unroll
  for (int k = 0; k < 16; ++k) wb[ob + 17*k] = xr[k];
  WBAR();
#pragma unroll
  for (int m = 0; m < 4; ++m)
#pragma unroll
    for (int k = 0; k < 4; ++k) xr[m + 4*k] = wb[base2 + 68*m + 272*k];
  WBAR();
#pragma unroll
  for (int k = 0; k < 16; ++k) wb[ob + 17*k] = xi[k];
  WBAR();
#pragma unroll
  for (int m = 0; m < 4; ++m)
#pragma unroll
    for (int k = 0; k < 4; ++k) xi[m + 4*k] = wb[base2 + 68*m + 272*k];
  WBAR();
#pragma unroll
  for (int m = 0; m < 4; ++m) {        // stage 3 (Ns=256, radix-4), in-place
    float ar[4], ai_[4];
#pragma unroll
    for (int k = 0; k < 4; ++k) { ar[k] = xr[m + 4*k]; ai_[k] = xi[m + 4*k]; }
    const int j = l + 64*m;
#pragma unroll
    for (int k = 1; k < 4; ++k) {
      float2 w = twg[j * k];
      CMUL(ar[k], ai_[k], ar[k], ai_[k], w.x, w.y);
    }
    RADIX4(ar[0],ai_[0], ar[1],ai_[1], ar[2],ai_[2], ar[3],ai_[3],
           xr[m],xi[m], xr[m+4],xi[m+4], xr[m+8],xi[m+8], xr[m+12],xi[m+12]);
  }
}

__global__ void k_init(float2* __restrict__ tw, int* __restrict__ slots) {
  int g = blockIdx.x * 256 + threadIdx.x;   // 0..2047
  if (g < 1024) {
    float ang = -6.283185307179586f * ((float)g / 1024.0f);
    float s, c;
    sincosf(ang, &s, &c);
    tw[g] = make_float2(c, s);
    slots[g] = 0x7F800000;                  // +inf (min slots, 16 b x 64 slices)
  } else {
    slots[g] = 0;                           // 0 (max slots; spec >= 0)
  }
}

// Pass 1 (R7 kernel + XCD-swizzle): 8 waves/block, 16 rows, 1-buffer FFT,
// Hermitian unpack + transposed staging in two v-halves, 128B transposed
// chunks. NEW: block index remap so all 64 h-blocks of one image land on ONE
// XCD (dispatch round-robins XCDs by blockIdx&7) — the 64 writers of each A
// row then share a single L2, letting full 8KB rows aggregate before
// writeback instead of 8 L2s each evicting a sparse 1/8 comb of every row.
__global__ __launch_bounds__(512, 6) void k_rowfft(const float* __restrict__ in,
                                                   float2* __restrict__ A,
                                                   const float2* __restrict__ twg) {
  __shared__ float lds[8704];          // 8 waves x 1088; overlaid: stg [16][260] x2
  const int t  = threadIdx.x;
  const int w  = t >> 6;               // 0..7
  const int l  = t & 63;
  // XCD-swizzle: j&7 = XCD; XCD x owns images 6x..6x+5 (bijective over 3072)
  const int j   = blockIdx.x;
  const int q   = j >> 3;
  const int bc  = (j & 7) * 6 + (q >> 6);   // image 0..47
  const int h0b = (q & 63) << 4;            // 16 rows per block
  const int r0  = h0b + 2 * w;
  float* wb = lds + w * 1088;
  const float* row0 = in + ((size_t)bc << 20) + ((size_t)r0 << 10);
  const float* row1 = row0 + N;
  float xr[16], xi[16];
  const float sgn = (l & 1) ? -1.0f : 1.0f;   // fftshift sign (-1)^h
#pragma unroll
  for (int k = 0; k < 16; ++k) {
    xr[k] =  sgn * row0[l + 64*k];
    xi[k] = -sgn * row1[l + 64*k];
  }
  wave_fft1024_1buf(xr, xi, wb, twg, l);
  // Hermitian unpack A=(P+conj(Q))/2, B=-i(P-conj(Q))/2, Q=Z[(N-i)&1023],
  // staged + written per v-half; Z re-staged per half from register xr/xi.
  float* stre = lds;                   // [16][260]
  float* stim = lds + 4160;            // [16][260]
  const int rr = t & 15, v0 = t >> 4;  // 128B transposed chunk coords
  float2* Abc = A + ((size_t)bc << 20);
#pragma unroll
  for (int h = 0; h < 2; ++h) {
    const int slo = (h == 0) ? 0 : 4;
    const int cnt = (h == 0) ? 4 : 5;
    float par[5], pai[5], pbr[5], pbi[5];
    __syncthreads();
#pragma unroll
    for (int s = 0; s < 16; ++s) wb[l + 64*s] = xr[s];
    WBAR();
#pragma unroll
    for (int u = 0; u < 5; ++u) {
      if (u < cnt) {
        int s = slo + u;
        int i = l + 64*s;
        if (i <= 512) {
          float qr = wb[(N - i) & (N - 1)];
          par[u] = 0.5f * (xr[s] + qr);
          pbi[u] = 0.5f * (qr - xr[s]);
        }
      }
    }
    WBAR();
#pragma unroll
    for (int s = 0; s < 16; ++s) wb[l + 64*s] = xi[s];
    WBAR();
#pragma unroll
    for (int u = 0; u < 5; ++u) {
      if (u < cnt) {
        int s = slo + u;
        int i = l + 64*s;
        if (i <= 512) {
          float qi = wb[(N - i) & (N - 1)];
          pai[u] = 0.5f * (xi[s] - qi);
          pbr[u] = 0.5f * (xi[s] + qi);
        }
      }
    }
    __syncthreads();
#pragma unroll
    for (int u = 0; u < 5; ++u) {
      if (u < cnt) {
        int s = slo + u;
        int i = l + 64*s;
        if (i <= 512) {
          int c = i - 256 * h;
          stre[(2*w)     * 260 + c] = par[u]; stim[(2*w)     * 260 + c] = pai[u];
          stre[(2*w + 1) * 260 + c] = pbr[u]; stim[(2*w + 1) * 260 + c] = pbi[u];
        }
      }
    }
    __syncthreads();
#pragma unroll
    for (int i2 = 0; i2 < 9; ++i2) {
      if (i2 < 8 + h) {
        int v = 256 * h + v0 + 32 * i2;
        if (v <= 512) {
          int c = v - 256 * h;
          Abc[(size_t)v * N + h0b + rr] =
              make_float2(stre[rr*260 + c], stim[rr*260 + c]);
        }
      }
    }
  }
}

// Pass 2 (R4-exact): fused column FFT (1-buffer, 17408 B/block -> 32 waves/CU)
// + spec + sliced minmax atomics + 10-tap fused resize (column sx, mirror N-sx).
__global__ __launch_bounds__(256, 8) void k_colfft(const float2* __restrict__ A,
                                                   float* __restrict__ WSf,
                                                   int* __restrict__ slots,
                                                   const float2* __restrict__ twg) {
  __shared__ float lds[4352];          // 4 waves x 1088
  const int t  = threadIdx.x;
  const int w  = t >> 6;
  const int l  = t & 63;
  const int gw = blockIdx.x * 4 + w;   // 0..24623 == BC*513-1 exactly
  const int bc = gw / 513;
  const int sx = gw - bc * 513;
  const int b  = bc / CH;
  float* wb = lds + w * 1088;
  const float2* src = A + ((size_t)bc << 20) + ((size_t)sx << 10);
  float xr[16], xi[16];
#pragma unroll
  for (int k = 0; k < 16; ++k) { float2 v = src[l + 64*k]; xr[k] = v.x; xi[k] = v.y; }
  wave_fft1024_1buf(xr, xi, wb, twg, l);
  float lmin = 3.4e38f, lmax = 0.0f;
#pragma unroll
  for (int s = 0; s < 16; ++s) {
    float sp = __logf(1.0f + sqrtf(xr[s]*xr[s] + xi[s]*xi[s]));
    wb[l + 64*s] = sp;                 // spec plain-indexed in own buffer
    lmin = fminf(lmin, sp); lmax = fmaxf(lmax, sp);
  }
#pragma unroll
  for (int off = 32; off; off >>= 1) {
    lmin = fminf(lmin, __shfl_xor(lmin, off));
    lmax = fmaxf(lmax, __shfl_xor(lmax, off));
  }
  if (l == 0) {                        // spread over 64 slices/image
    atomicMin(&slots[b * 64 + (sx & 63)],        __float_as_int(lmin));
    atomicMax(&slots[1024 + b * 64 + (sx & 63)], __float_as_int(lmax));
  }
  WBAR();
  float* T1 = WSf + ((size_t)bc << 21) + T1OFF;
  const bool mir = (sx != 0) && (sx != 512);
#pragma unroll
  for (int obk = 0; obk < 4; ++obk) {
    int oh = l + 64 * obk;
    if (oh < OUTHW) {
      float x = ((float)oh + 0.5f) * KSCALE - 0.5f;
      int jlo = (int)ceilf(x - KSCALE);           // unclamped; window < 10 taps
      float ssum = 0.0f, acc = 0.0f, accm = 0.0f;
#pragma unroll
      for (int u = 0; u < 10; ++u) {
        int jj = jlo + u;
        float wgt = 1.0f - fabsf((float)jj - x) * SCALE;
        wgt = fmaxf(wgt, 0.0f);
        bool valid = (jj >= 0) && (jj <= N - 1);
        if (!valid) wgt = 0.0f;
        int ja = valid ? jj : 0;
        ssum += wgt;
        acc  += wgt * wb[ja];
        accm += wgt * wb[(N - ja) & (N - 1)];
      }
      float inv = 1.0f / ssum;
      T1[(size_t)sx * OUTHW + oh] = acc * inv;
      if (mir) T1[(size_t)(N - sx) * OUTHW + oh] = accm * inv;
    }
  }
}

// Pass 3 (R6-exact): contract v + normalization; direct coalesced T1 reads,
// fixed 10-tap unrolled loop, slot min/max reduction merged in.
__global__ __launch_bounds__(256) void k_resize2(const float2* __restrict__ A,
                                                 const int* __restrict__ slots,
                                                 float* __restrict__ out) {
  __shared__ float s2[2];
  const int ow = blockIdx.x % OUTHW;
  const int bc = blockIdx.x / OUTHW;
  const int b  = bc / CH;
  const int t  = threadIdx.x;
  if (t < 64) {
    int mn = slots[b * 64 + t];
#pragma unroll
    for (int off = 32; off; off >>= 1) mn = min(mn, __shfl_xor(mn, off));
    if (t == 0) s2[0] = __int_as_float(mn);
  } else if (t < 128) {
    int mx = slots[1024 + b * 64 + (t - 64)];
#pragma unroll
    for (int off = 32; off; off >>= 1) mx = max(mx, __shfl_xor(mx, off));
    if (t == 64) s2[1] = __int_as_float(mx);
  }
  __syncthreads();
  if (t >= OUTHW) return;
  const float mn = s2[0];
  const float mx = s2[1];
  const float inv = 1.0f / (mx - mn + 1e-8f);
  const float* T1 = (const float*)(A + ((size_t)bc << 20)) + T1OFF;
  float x = ((float)ow + 0.5f) * KSCALE - 0.5f;
  int jlo = (int)ceilf(x - KSCALE);              // unclamped; window < 10 taps
  float ssum = 0.0f, acc = 0.0f;
#pragma unroll
  for (int u = 0; u < 10; ++u) {
    int jj = jlo + u;
    float wv = 1.0f - fabsf((float)jj - x) * SCALE;
    wv = fmaxf(wv, 0.0f);
    bool valid = (jj >= 0) && (jj <= N - 1);
    if (!valid) wv = 0.0f;
    int ja = valid ? jj : 0;                     // row 0 always valid memory
    ssum += wv;
    acc += wv * T1[(size_t)ja * OUTHW + t];      // coalesced 896B per tap row
  }
  float v = acc / ssum;
  out[((size_t)bc * OUTHW + t) * OUTHW + ow] = (v - mn) * inv;
}

extern "C" void kernel_launch(void* const* d_in, const int* in_sizes, int n_in,
                              void* d_out, int out_size, void* d_ws, size_t ws_size,
                              hipStream_t stream) {
  const float* in = (const float*)d_in[0];
  float* out = (float*)d_out;
  float2* A = (float2*)d_ws;
  float* WSf = (float*)d_ws;
  float2* twg = (float2*)((char*)d_ws + ABYTES + 128);
  int* slots = (int*)(WSf + SLOTOFF);          // slab-0 tail, after T1

  k_init<<<8, 256, 0, stream>>>(twg, slots);
  k_rowfft<<<BC * 64, 512, 0, stream>>>(in, A, twg);
  k_colfft<<<(BC * 513) / 4, 256, 0, stream>>>(A, WSf, slots, twg);
  k_resize2<<<BC * OUTHW, 256, 0, stream>>>(A, slots, out);
}

// Round 11
// 419.761 us; speedup vs baseline: 1.1616x; 1.0264x over previous
//
#include <hip/hip_runtime.h>
#include <hip/hip_fp16.h>
#include <math.h>

#define N 1024
#define BATCH 16
#define CH 3
#define BC 48
#define OUTHW 224
#define KSCALE (1024.0f / 224.0f)
#define SCALE  (224.0f / 1024.0f)
#define ABYTES ((size_t)BC * N * N * 8)      // legacy ws offset for twg (ws >= this)
// ---- disjoint workspace layout (byte ranges verified non-overlapping) ----
// A   (half2): [0, 100,859,904)                48 x 525,312 half2 (2.101 MB each)
// T1  (float): [100,859,904, 144,900,096)      48 x 229,376 floats
// slots (int): [144,900,096, 144,908,288)      2048 ints
// twg (float2): [ABYTES+128, +8 KB)            unchanged
#define AST    525312                        // half2 per image (513*1024), dense
#define T1BASE 25214976                      // float offset of T1 region
#define T1SZ   (OUTHW * N)                   // 229376 floats per bc
#define SLOTBASE 36225024                    // float offset of slots
#define WBAR() __builtin_amdgcn_wave_barrier()

// (ar,ai)*(br,bi) -> (dr,di); safe when d aliases a
#define CMUL(dr, di, ar, ai, br, bi) do {                         \
    float _r = (ar) * (br) - (ai) * (bi);                         \
    float _i = (ar) * (bi) + (ai) * (br);                         \
    (dr) = _r; (di) = _i; } while (0)

// forward DFT-4
#define RADIX4(ar,ai,br,bi,cr,ci,dr,di, o0r,o0i,o1r,o1i,o2r,o2i,o3r,o3i) do { \
    float u0r=(ar)+(cr), u0i=(ai)+(ci);                           \
    float u1r=(ar)-(cr), u1i=(ai)-(ci);                           \
    float u2r=(br)+(dr), u2i=(bi)+(di);                           \
    float u3r=(bi)-(di), u3i=(dr)-(br);                           \
    (o0r)=u0r+u2r; (o0i)=u0i+u2i;                                 \
    (o1r)=u1r+u3r; (o1i)=u1i+u3i;                                 \
    (o2r)=u0r-u2r; (o2i)=u0i-u2i;                                 \
    (o3r)=u1r-u3r; (o3i)=u1i-u3i; } while (0)

// In-register natural-order 16-pt forward DFT (Stockham radix-4 x radix-4).
__device__ __forceinline__ void dft16(float* xr, float* xi) {
  const float W16R[4][4] = {
    {1.f, 1.f, 1.f, 1.f},
    {1.f,  0.9238795325f,  0.7071067812f,  0.3826834324f},
    {1.f,  0.7071067812f,  0.0f,          -0.7071067812f},
    {1.f,  0.3826834324f, -0.7071067812f, -0.9238795325f}};
  const float W16I[4][4] = {
    {0.f, 0.f, 0.f, 0.f},
    {0.f, -0.3826834324f, -0.7071067812f, -0.9238795325f},
    {0.f, -0.7071067812f, -1.0f,          -0.7071067812f},
    {0.f, -0.9238795325f, -0.7071067812f,  0.3826834324f}};
  float tr[16], ti[16];
#pragma unroll
  for (int j = 0; j < 4; ++j) {
    RADIX4(xr[j],xi[j], xr[j+4],xi[j+4], xr[j+8],xi[j+8], xr[j+12],xi[j+12],
           tr[4*j],ti[4*j], tr[4*j+1],ti[4*j+1], tr[4*j+2],ti[4*j+2], tr[4*j+3],ti[4*j+3]);
  }
#pragma unroll
  for (int j = 0; j < 4; ++j) {
    float ar[4], ai_[4];
#pragma unroll
    for (int k = 0; k < 4; ++k) {
      if (j == 0 || k == 0) { ar[k] = tr[j+4*k]; ai_[k] = ti[j+4*k]; }
      else CMUL(ar[k], ai_[k], tr[j+4*k], ti[j+4*k], W16R[j][k], W16I[j][k]);
    }
    RADIX4(ar[0],ai_[0], ar[1],ai_[1], ar[2],ai_[2], ar[3],ai_[3],
           xr[j],xi[j], xr[j+4],xi[j+4], xr[j+8],xi[j+8], xr[j+12],xi[j+12]);
  }
}

__device__ __forceinline__ void stage2(float* xr, float* xi,
                                       const float2* __restrict__ twg, int j2) {
#pragma unroll
  for (int k = 1; k < 16; ++k) {       // twiddle W256^{j2*k}
    float2 w = twg[4 * j2 * k];
    CMUL(xr[k], xi[k], xr[k], xi[k], w.x, w.y);
  }
  dft16(xr, xi);
}

// 1-buffer wave FFT (R4-proven): sequential re/im round-trips through ONE
// 1088-float buffer (in-order DS pipe). Ex2 gather lands at slots xr[m+4k],
// making stage 3 an exact in-place butterfly.
__device__ __forceinline__ void wave_fft1024_1buf(float* xr, float* xi,
                                                  float* wb,
                                                  const float2* __restrict__ twg,
                                                  int l) {
  const int base2 = l + (l >> 4);
  const int j2 = l & 15;
  const int ob = 272 * (l >> 4) + j2;
  dft16(xr, xi);                       // stage 1 (Ns=1)
#pragma unroll
  for (int k = 0; k < 16; ++k) wb[17*l + k] = xr[k];
  WBAR();
#pragma unroll
  for (int k = 0; k < 16; ++k) xr[k] = wb[base2 + 68*k];
  WBAR();
#pragma unroll
  for (int k = 0; k < 16; ++k) wb[17*l + k] = xi[k];
  WBAR();
#pragma unroll
  for (int k = 0; k < 16; ++k) xi[k] = wb[base2 + 68*k];
  WBAR();
  stage2(xr, xi, twg, j2);             // stage 2 (Ns=16)
#pragma unroll
  for (int k = 0; k < 16; ++k) wb[ob + 17*k] = xr[k];
  WBAR();
#pragma unroll
  for (int m = 0; m < 4; ++m)
#pragma unroll
    for (int k = 0; k < 4; ++k) xr[m + 4*k] = wb[base2 + 68*m + 272*k];
  WBAR();
#pragma unroll
  for (int k = 0; k < 16; ++k) wb[ob + 17*k] = xi[k];
  WBAR();
#pragma unroll
  for (int m = 0; m < 4; ++m)
#pragma unroll
    for (int k = 0; k < 4; ++k) xi[m + 4*k] = wb[base2 + 68*m + 272*k];
  WBAR();
#pragma unroll
  for (int m = 0; m < 4; ++m) {        // stage 3 (Ns=256, radix-4), in-place
    float ar[4], ai_[4];
#pragma unroll
    for (int k = 0; k < 4; ++k) { ar[k] = xr[m + 4*k]; ai_[k] = xi[m + 4*k]; }
    const int j = l + 64*m;
#pragma unroll
    for (int k = 1; k < 4; ++k) {
      float2 w = twg[j * k];
      CMUL(ar[k], ai_[k], ar[k], ai_[k], w.x, w.y);
    }
    RADIX4(ar[0],ai_[0], ar[1],ai_[1], ar[2],ai_[2], ar[3],ai_[3],
           xr[m],xi[m], xr[m+4],xi[m+4], xr[m+8],xi[m+8], xr[m+12],xi[m+12]);
  }
}

__global__ void k_init(float2* __restrict__ tw, int* __restrict__ slots) {
  int g = blockIdx.x * 256 + threadIdx.x;   // 0..2047
  if (g < 1024) {
    float ang = -6.283185307179586f * ((float)g / 1024.0f);
    float s, c;
    sincosf(ang, &s, &c);
    tw[g] = make_float2(c, s);
    slots[g] = 0x7F800000;                  // +inf (min slots, 16 b x 64 slices)
  } else {
    slots[g] = 0;                           // 0 (max slots; spec >= 0)
  }
}

// Pass 1 (R10 structure; fixed A layout): 8 waves/block, 16 rows, 1-buffer
// FFT, Hermitian unpack + transposed staging in two v-halves, XCD swizzle.
// A element = __half2(re,im), dense 2.101 MB/image stride — half the write
// bytes (rowfft runs at fixed ~2.45 TB/s regardless of pattern, R7/R8/R9).
__global__ __launch_bounds__(512, 6) void k_rowfft(const float* __restrict__ in,
                                                   __half2* __restrict__ A,
                                                   const float2* __restrict__ twg) {
  __shared__ float lds[8704];          // 8 waves x 1088; overlaid: stg [16][260] x2
  const int t  = threadIdx.x;
  const int w  = t >> 6;               // 0..7
  const int l  = t & 63;
  // XCD-swizzle (kept from R9, harmless): j&7 = XCD owns images 6x..6x+5
  const int j   = blockIdx.x;
  const int q   = j >> 3;
  const int bc  = (j & 7) * 6 + (q >> 6);   // image 0..47
  const int h0b = (q & 63) << 4;            // 16 rows per block
  const int r0  = h0b + 2 * w;
  float* wb = lds + w * 1088;
  const float* row0 = in + ((size_t)bc << 20) + ((size_t)r0 << 10);
  const float* row1 = row0 + N;
  float xr[16], xi[16];
  const float sgn = (l & 1) ? -1.0f : 1.0f;   // fftshift sign (-1)^h
#pragma unroll
  for (int k = 0; k < 16; ++k) {
    xr[k] =  sgn * row0[l + 64*k];
    xi[k] = -sgn * row1[l + 64*k];
  }
  wave_fft1024_1buf(xr, xi, wb, twg, l);
  // Hermitian unpack A=(P+conj(Q))/2, B=-i(P-conj(Q))/2, Q=Z[(N-i)&1023],
  // staged + written per v-half; Z re-staged per half from register xr/xi.
  float* stre = lds;                   // [16][260]
  float* stim = lds + 4160;            // [16][260]
  const int rr = t & 15, v0 = t >> 4;  // transposed chunk coords (64B chunks)
  __half2* Abc = A + (size_t)bc * AST; // dense slab, no T1 aliasing (R10 bug)
#pragma unroll
  for (int h = 0; h < 2; ++h) {
    const int slo = (h == 0) ? 0 : 4;
    const int cnt = (h == 0) ? 4 : 5;
    float par[5], pai[5], pbr[5], pbi[5];
    __syncthreads();
#pragma unroll
    for (int s = 0; s < 16; ++s) wb[l + 64*s] = xr[s];
    WBAR();
#pragma unroll
    for (int u = 0; u < 5; ++u) {
      if (u < cnt) {
        int s = slo + u;
        int i = l + 64*s;
        if (i <= 512) {
          float qr = wb[(N - i) & (N - 1)];
          par[u] = 0.5f * (xr[s] + qr);
          pbi[u] = 0.5f * (qr - xr[s]);
        }
      }
    }
    WBAR();
#pragma unroll
    for (int s = 0; s < 16; ++s) wb[l + 64*s] = xi[s];
    WBAR();
#pragma unroll
    for (int u = 0; u < 5; ++u) {
      if (u < cnt) {
        int s = slo + u;
        int i = l + 64*s;
        if (i <= 512) {
          float qi = wb[(N - i) & (N - 1)];
          pai[u] = 0.5f * (xi[s] - qi);
          pbr[u] = 0.5f * (xi[s] + qi);
        }
      }
    }
    __syncthreads();
#pragma unroll
    for (int u = 0; u < 5; ++u) {
      if (u < cnt) {
        int s = slo + u;
        int i = l + 64*s;
        if (i <= 512) {
          int c = i - 256 * h;
          stre[(2*w)     * 260 + c] = par[u]; stim[(2*w)     * 260 + c] = pai[u];
          stre[(2*w + 1) * 260 + c] = pbr[u]; stim[(2*w + 1) * 260 + c] = pbi[u];
        }
      }
    }
    __syncthreads();
#pragma unroll
    for (int i2 = 0; i2 < 9; ++i2) {
      if (i2 < 8 + h) {
        int v = 256 * h + v0 + 32 * i2;
        if (v <= 512) {
          int c = v - 256 * h;
          Abc[(size_t)v * N + h0b + rr] =
              __floats2half2_rn(stre[rr*260 + c], stim[rr*260 + c]);
        }
      }
    }
  }
}

// Pass 2 (R10 structure; fixed layout): fused column FFT (1-buffer) + spec +
// sliced minmax atomics + 10-tap fused resize (column sx, mirror N-sx).
__global__ __launch_bounds__(256, 8) void k_colfft(const __half2* __restrict__ A,
                                                   float* __restrict__ WSf,
                                                   int* __restrict__ slots,
                                                   const float2* __restrict__ twg) {
  __shared__ float lds[4352];          // 4 waves x 1088
  const int t  = threadIdx.x;
  const int w  = t >> 6;
  const int l  = t & 63;
  const int gw = blockIdx.x * 4 + w;   // 0..24623 == BC*513-1 exactly
  const int bc = gw / 513;
  const int sx = gw - bc * 513;
  const int b  = bc / CH;
  float* wb = lds + w * 1088;
  const __half2* src = A + (size_t)bc * AST + ((size_t)sx << 10);
  float xr[16], xi[16];
#pragma unroll
  for (int k = 0; k < 16; ++k) {
    float2 v = __half22float2(src[l + 64*k]);
    xr[k] = v.x; xi[k] = v.y;
  }
  wave_fft1024_1buf(xr, xi, wb, twg, l);
  float lmin = 3.4e38f, lmax = 0.0f;
#pragma unroll
  for (int s = 0; s < 16; ++s) {
    float sp = __logf(1.0f + sqrtf(xr[s]*xr[s] + xi[s]*xi[s]));
    wb[l + 64*s] = sp;                 // spec plain-indexed in own buffer
    lmin = fminf(lmin, sp); lmax = fmaxf(lmax, sp);
  }
#pragma unroll
  for (int off = 32; off; off >>= 1) {
    lmin = fminf(lmin, __shfl_xor(lmin, off));
    lmax = fmaxf(lmax, __shfl_xor(lmax, off));
  }
  if (l == 0) {                        // spread over 64 slices/image
    atomicMin(&slots[b * 64 + (sx & 63)],        __float_as_int(lmin));
    atomicMax(&slots[1024 + b * 64 + (sx & 63)], __float_as_int(lmax));
  }
  WBAR();
  float* T1 = WSf + T1BASE + (size_t)bc * T1SZ;
  const bool mir = (sx != 0) && (sx != 512);
#pragma unroll
  for (int obk = 0; obk < 4; ++obk) {
    int oh = l + 64 * obk;
    if (oh < OUTHW) {
      float x = ((float)oh + 0.5f) * KSCALE - 0.5f;
      int jlo = (int)ceilf(x - KSCALE);           // unclamped; window < 10 taps
      float ssum = 0.0f, acc = 0.0f, accm = 0.0f;
#pragma unroll
      for (int u = 0; u < 10; ++u) {
        int jj = jlo + u;
        float wgt = 1.0f - fabsf((float)jj - x) * SCALE;
        wgt = fmaxf(wgt, 0.0f);
        bool valid = (jj >= 0) && (jj <= N - 1);
        if (!valid) wgt = 0.0f;
        int ja = valid ? jj : 0;
        ssum += wgt;
        acc  += wgt * wb[ja];
        accm += wgt * wb[(N - ja) & (N - 1)];
      }
      float inv = 1.0f / ssum;
      T1[(size_t)sx * OUTHW + oh] = acc * inv;
      if (mir) T1[(size_t)(N - sx) * OUTHW + oh] = accm * inv;
    }
  }
}

// Pass 3 (R6 structure; new T1 region): contract v + normalization; direct
// coalesced T1 reads, fixed 10-tap unrolled loop, slot reduction merged in.
__global__ __launch_bounds__(256) void k_resize2(const float* __restrict__ WSf,
                                                 const int* __restrict__ slots,
                                                 float* __restrict__ out) {
  __shared__ float s2[2];
  const int ow = blockIdx.x % OUTHW;
  const int bc = blockIdx.x / OUTHW;
  const int b  = bc / CH;
  const int t  = threadIdx.x;
  if (t < 64) {
    int mn = slots[b * 64 + t];
#pragma unroll
    for (int off = 32; off; off >>= 1) mn = min(mn, __shfl_xor(mn, off));
    if (t == 0) s2[0] = __int_as_float(mn);
  } else if (t < 128) {
    int mx = slots[1024 + b * 64 + (t - 64)];
#pragma unroll
    for (int off = 32; off; off >>= 1) mx = max(mx, __shfl_xor(mx, off));
    if (t == 64) s2[1] = __int_as_float(mx);
  }
  __syncthreads();
  if (t >= OUTHW) return;
  const float mn = s2[0];
  const float mx = s2[1];
  const float inv = 1.0f / (mx - mn + 1e-8f);
  const float* T1 = WSf + T1BASE + (size_t)bc * T1SZ;
  float x = ((float)ow + 0.5f) * KSCALE - 0.5f;
  int jlo = (int)ceilf(x - KSCALE);              // unclamped; window < 10 taps
  float ssum = 0.0f, acc = 0.0f;
#pragma unroll
  for (int u = 0; u < 10; ++u) {
    int jj = jlo + u;
    float wv = 1.0f - fabsf((float)jj - x) * SCALE;
    wv = fmaxf(wv, 0.0f);
    bool valid = (jj >= 0) && (jj <= N - 1);
    if (!valid) wv = 0.0f;
    int ja = valid ? jj : 0;                     // row 0 always valid memory
    ssum += wv;
    acc += wv * T1[(size_t)ja * OUTHW + t];      // coalesced 896B per tap row
  }
  float v = acc / ssum;
  out[((size_t)bc * OUTHW + t) * OUTHW + ow] = (v - mn) * inv;
}

extern "C" void kernel_launch(void* const* d_in, const int* in_sizes, int n_in,
                              void* d_out, int out_size, void* d_ws, size_t ws_size,
                              hipStream_t stream) {
  const float* in = (const float*)d_in[0];
  float* out = (float*)d_out;
  __half2* A = (__half2*)d_ws;                 // dense fp16 A region [0, 100.9MB)
  float* WSf = (float*)d_ws;
  float2* twg = (float2*)((char*)d_ws + ABYTES + 128);
  int* slots = (int*)(WSf + SLOTBASE);         // [144.9MB, +8KB)

  k_init<<<8, 256, 0, stream>>>(twg, slots);
  k_rowfft<<<BC * 64, 512, 0, stream>>>(in, A, twg);
  k_colfft<<<(BC * 513) / 4, 256, 0, stream>>>(A, WSf, slots, twg);
  k_resize2<<<BC * OUTHW, 256, 0, stream>>>(WSf, slots, out);
}

// Round 12
// 405.355 us; speedup vs baseline: 1.2029x; 1.0355x over previous
//
#include <hip/hip_runtime.h>
#include <hip/hip_fp16.h>
#include <math.h>

#define N 1024
#define BATCH 16
#define CH 3
#define BC 48
#define OUTHW 224
#define KSCALE (1024.0f / 224.0f)
#define SCALE  (224.0f / 1024.0f)
// ---- disjoint workspace layout (byte ranges verified non-overlapping) ----
// A   (half2): [0, 100,859,904)                48 x 525,312 half2 (2.101 MB each)
// T1  (float): [100,859,904, 144,900,096)      48 x 229,376 floats
// slots (int): [144,900,096, 144,908,288)      2048 ints
#define AST    525312                        // half2 per image (513*1024), dense
#define T1BASE 25214976                      // float offset of T1 region
#define T1SZ   (OUTHW * N)                   // 229376 floats per bc
#define SLOTBASE 36225024                    // float offset of slots
#define TWOPI 6.283185307179586f
#define WBAR() __builtin_amdgcn_wave_barrier()

// (ar,ai)*(br,bi) -> (dr,di); safe when d aliases a
#define CMUL(dr, di, ar, ai, br, bi) do {                         \
    float _r = (ar) * (br) - (ai) * (bi);                         \
    float _i = (ar) * (bi) + (ai) * (br);                         \
    (dr) = _r; (di) = _i; } while (0)

// forward DFT-4
#define RADIX4(ar,ai,br,bi,cr,ci,dr,di, o0r,o0i,o1r,o1i,o2r,o2i,o3r,o3i) do { \
    float u0r=(ar)+(cr), u0i=(ai)+(ci);                           \
    float u1r=(ar)-(cr), u1i=(ai)-(ci);                           \
    float u2r=(br)+(dr), u2i=(bi)+(di);                           \
    float u3r=(bi)-(di), u3i=(dr)-(br);                           \
    (o0r)=u0r+u2r; (o0i)=u0i+u2i;                                 \
    (o1r)=u1r+u3r; (o1i)=u1i+u3i;                                 \
    (o2r)=u0r-u2r; (o2i)=u0i-u2i;                                 \
    (o3r)=u1r-u3r; (o3i)=u1i-u3i; } while (0)

// In-register natural-order 16-pt forward DFT (Stockham radix-4 x radix-4).
__device__ __forceinline__ void dft16(float* xr, float* xi) {
  const float W16R[4][4] = {
    {1.f, 1.f, 1.f, 1.f},
    {1.f,  0.9238795325f,  0.7071067812f,  0.3826834324f},
    {1.f,  0.7071067812f,  0.0f,          -0.7071067812f},
    {1.f,  0.3826834324f, -0.7071067812f, -0.9238795325f}};
  const float W16I[4][4] = {
    {0.f, 0.f, 0.f, 0.f},
    {0.f, -0.3826834324f, -0.7071067812f, -0.9238795325f},
    {0.f, -0.7071067812f, -1.0f,          -0.7071067812f},
    {0.f, -0.9238795325f, -0.7071067812f,  0.3826834324f}};
  float tr[16], ti[16];
#pragma unroll
  for (int j = 0; j < 4; ++j) {
    RADIX4(xr[j],xi[j], xr[j+4],xi[j+4], xr[j+8],xi[j+8], xr[j+12],xi[j+12],
           tr[4*j],ti[4*j], tr[4*j+1],ti[4*j+1], tr[4*j+2],ti[4*j+2], tr[4*j+3],ti[4*j+3]);
  }
#pragma unroll
  for (int j = 0; j < 4; ++j) {
    float ar[4], ai_[4];
#pragma unroll
    for (int k = 0; k < 4; ++k) {
      if (j == 0 || k == 0) { ar[k] = tr[j+4*k]; ai_[k] = ti[j+4*k]; }
      else CMUL(ar[k], ai_[k], tr[j+4*k], ti[j+4*k], W16R[j][k], W16I[j][k]);
    }
    RADIX4(ar[0],ai_[0], ar[1],ai_[1], ar[2],ai_[2], ar[3],ai_[3],
           xr[j],xi[j], xr[j+4],xi[j+4], xr[j+8],xi[j+8], xr[j+12],xi[j+12]);
  }
}

// Stage 2 with REGISTER twiddles: W256^{j2*k} built from one sincos + a
// 14-CMUL recurrence (error ~15 ulp, << fp16 A error). No memory traffic.
__device__ __forceinline__ void stage2_reg(float* xr, float* xi, int j2) {
  float s1, c1;
  __sincosf(-TWOPI * (float)j2 * (1.0f / 256.0f), &s1, &c1);
  float wr = c1, wi = s1;
#pragma unroll
  for (int k = 1; k < 16; ++k) {
    CMUL(xr[k], xi[k], xr[k], xi[k], wr, wi);
    if (k < 15) CMUL(wr, wi, wr, wi, c1, s1);   // w^{k+1}
  }
  dft16(xr, xi);
}

// 1-buffer wave FFT (R4-proven structure; twiddles now in registers).
// Sequential re/im round-trips through ONE 1088-float buffer (in-order DS
// pipe). Ex2 gather lands at slots xr[m+4k] -> stage 3 exactly in-place.
// Stage-3 twiddles: W1024^{(l+64m)k} = (W1024^l * W16^m)^k, W16^m constants.
__device__ __forceinline__ void wave_fft1024_1buf(float* xr, float* xi,
                                                  float* wb, int l) {
  const int base2 = l + (l >> 4);
  const int j2 = l & 15;
  const int ob = 272 * (l >> 4) + j2;
  dft16(xr, xi);                       // stage 1 (Ns=1)
#pragma unroll
  for (int k = 0; k < 16; ++k) wb[17*l + k] = xr[k];
  WBAR();
#pragma unroll
  for (int k = 0; k < 16; ++k) xr[k] = wb[base2 + 68*k];
  WBAR();
#pragma unroll
  for (int k = 0; k < 16; ++k) wb[17*l + k] = xi[k];
  WBAR();
#pragma unroll
  for (int k = 0; k < 16; ++k) xi[k] = wb[base2 + 68*k];
  WBAR();
  stage2_reg(xr, xi, j2);              // stage 2 (Ns=16)
#pragma unroll
  for (int k = 0; k < 16; ++k) wb[ob + 17*k] = xr[k];
  WBAR();
#pragma unroll
  for (int m = 0; m < 4; ++m)
#pragma unroll
    for (int k = 0; k < 4; ++k) xr[m + 4*k] = wb[base2 + 68*m + 272*k];
  WBAR();
#pragma unroll
  for (int k = 0; k < 16; ++k) wb[ob + 17*k] = xi[k];
  WBAR();
#pragma unroll
  for (int m = 0; m < 4; ++m)
#pragma unroll
    for (int k = 0; k < 4; ++k) xi[m + 4*k] = wb[base2 + 68*m + 272*k];
  WBAR();
  // W1024^l once per FFT (register twiddle base for stage 3)
  float sl, cl;
  __sincosf(-TWOPI * (float)l * (1.0f / 1024.0f), &sl, &cl);
  const float W16mR[4] = {1.f,  0.9238795325f,  0.7071067812f,  0.3826834324f};
  const float W16mI[4] = {0.f, -0.3826834324f, -0.7071067812f, -0.9238795325f};
#pragma unroll
  for (int m = 0; m < 4; ++m) {        // stage 3 (Ns=256, radix-4), in-place
    float ar[4], ai_[4];
#pragma unroll
    for (int k = 0; k < 4; ++k) { ar[k] = xr[m + 4*k]; ai_[k] = xi[m + 4*k]; }
    float w1r, w1i, w2r, w2i, w3r, w3i;
    CMUL(w1r, w1i, cl, sl, W16mR[m], W16mI[m]);  // W1024^{l+64m}
    CMUL(w2r, w2i, w1r, w1i, w1r, w1i);          // ^2
    CMUL(w3r, w3i, w2r, w2i, w1r, w1i);          // ^3
    CMUL(ar[1], ai_[1], ar[1], ai_[1], w1r, w1i);
    CMUL(ar[2], ai_[2], ar[2], ai_[2], w2r, w2i);
    CMUL(ar[3], ai_[3], ar[3], ai_[3], w3r, w3i);
    RADIX4(ar[0],ai_[0], ar[1],ai_[1], ar[2],ai_[2], ar[3],ai_[3],
           xr[m],xi[m], xr[m+4],xi[m+4], xr[m+8],xi[m+8], xr[m+12],xi[m+12]);
  }
}

__global__ void k_init(int* __restrict__ slots) {
  int g = blockIdx.x * 256 + threadIdx.x;   // 0..2047
  if (g < 1024) slots[g] = 0x7F800000;      // +inf (min slots, 16 b x 64 slices)
  else          slots[g] = 0;               // 0 (max slots; spec >= 0)
}

// Pass 1 (R11 structure; register twiddles): 8 waves/block, 16 rows, 1-buffer
// FFT, Hermitian unpack + transposed staging in two v-halves, XCD swizzle,
// dense fp16 A (half the write bytes).
__global__ __launch_bounds__(512, 6) void k_rowfft(const float* __restrict__ in,
                                                   __half2* __restrict__ A) {
  __shared__ float lds[8704];          // 8 waves x 1088; overlaid: stg [16][260] x2
  const int t  = threadIdx.x;
  const int w  = t >> 6;               // 0..7
  const int l  = t & 63;
  // XCD-swizzle: j&7 = XCD owns images 6x..6x+5
  const int j   = blockIdx.x;
  const int q   = j >> 3;
  const int bc  = (j & 7) * 6 + (q >> 6);   // image 0..47
  const int h0b = (q & 63) << 4;            // 16 rows per block
  const int r0  = h0b + 2 * w;
  float* wb = lds + w * 1088;
  const float* row0 = in + ((size_t)bc << 20) + ((size_t)r0 << 10);
  const float* row1 = row0 + N;
  float xr[16], xi[16];
  const float sgn = (l & 1) ? -1.0f : 1.0f;   // fftshift sign (-1)^h
#pragma unroll
  for (int k = 0; k < 16; ++k) {
    xr[k] =  sgn * row0[l + 64*k];
    xi[k] = -sgn * row1[l + 64*k];
  }
  wave_fft1024_1buf(xr, xi, wb, l);
  // Hermitian unpack A=(P+conj(Q))/2, B=-i(P-conj(Q))/2, Q=Z[(N-i)&1023],
  // staged + written per v-half; Z re-staged per half from register xr/xi.
  float* stre = lds;                   // [16][260]
  float* stim = lds + 4160;            // [16][260]
  const int rr = t & 15, v0 = t >> 4;  // transposed chunk coords (64B chunks)
  __half2* Abc = A + (size_t)bc * AST; // dense slab, disjoint from T1
#pragma unroll
  for (int h = 0; h < 2; ++h) {
    const int slo = (h == 0) ? 0 : 4;
    const int cnt = (h == 0) ? 4 : 5;
    float par[5], pai[5], pbr[5], pbi[5];
    __syncthreads();
#pragma unroll
    for (int s = 0; s < 16; ++s) wb[l + 64*s] = xr[s];
    WBAR();
#pragma unroll
    for (int u = 0; u < 5; ++u) {
      if (u < cnt) {
        int s = slo + u;
        int i = l + 64*s;
        if (i <= 512) {
          float qr = wb[(N - i) & (N - 1)];
          par[u] = 0.5f * (xr[s] + qr);
          pbi[u] = 0.5f * (qr - xr[s]);
        }
      }
    }
    WBAR();
#pragma unroll
    for (int s = 0; s < 16; ++s) wb[l + 64*s] = xi[s];
    WBAR();
#pragma unroll
    for (int u = 0; u < 5; ++u) {
      if (u < cnt) {
        int s = slo + u;
        int i = l + 64*s;
        if (i <= 512) {
          float qi = wb[(N - i) & (N - 1)];
          pai[u] = 0.5f * (xi[s] - qi);
          pbr[u] = 0.5f * (xi[s] + qi);
        }
      }
    }
    __syncthreads();
#pragma unroll
    for (int u = 0; u < 5; ++u) {
      if (u < cnt) {
        int s = slo + u;
        int i = l + 64*s;
        if (i <= 512) {
          int c = i - 256 * h;
          stre[(2*w)     * 260 + c] = par[u]; stim[(2*w)     * 260 + c] = pai[u];
          stre[(2*w + 1) * 260 + c] = pbr[u]; stim[(2*w + 1) * 260 + c] = pbi[u];
        }
      }
    }
    __syncthreads();
#pragma unroll
    for (int i2 = 0; i2 < 9; ++i2) {
      if (i2 < 8 + h) {
        int v = 256 * h + v0 + 32 * i2;
        if (v <= 512) {
          int c = v - 256 * h;
          Abc[(size_t)v * N + h0b + rr] =
              __floats2half2_rn(stre[rr*260 + c], stim[rr*260 + c]);
        }
      }
    }
  }
}

// Pass 2 (R11 structure; register twiddles): fused column FFT (1-buffer) +
// spec + sliced minmax atomics + 10-tap fused resize (column sx, mirror N-sx).
__global__ __launch_bounds__(256, 8) void k_colfft(const __half2* __restrict__ A,
                                                   float* __restrict__ WSf,
                                                   int* __restrict__ slots) {
  __shared__ float lds[4352];          // 4 waves x 1088
  const int t  = threadIdx.x;
  const int w  = t >> 6;
  const int l  = t & 63;
  const int gw = blockIdx.x * 4 + w;   // 0..24623 == BC*513-1 exactly
  const int bc = gw / 513;
  const int sx = gw - bc * 513;
  const int b  = bc / CH;
  float* wb = lds + w * 1088;
  const __half2* src = A + (size_t)bc * AST + ((size_t)sx << 10);
  float xr[16], xi[16];
#pragma unroll
  for (int k = 0; k < 16; ++k) {
    float2 v = __half22float2(src[l + 64*k]);
    xr[k] = v.x; xi[k] = v.y;
  }
  wave_fft1024_1buf(xr, xi, wb, l);
  float lmin = 3.4e38f, lmax = 0.0f;
#pragma unroll
  for (int s = 0; s < 16; ++s) {
    float sp = __logf(1.0f + sqrtf(xr[s]*xr[s] + xi[s]*xi[s]));
    wb[l + 64*s] = sp;                 // spec plain-indexed in own buffer
    lmin = fminf(lmin, sp); lmax = fmaxf(lmax, sp);
  }
#pragma unroll
  for (int off = 32; off; off >>= 1) {
    lmin = fminf(lmin, __shfl_xor(lmin, off));
    lmax = fmaxf(lmax, __shfl_xor(lmax, off));
  }
  if (l == 0) {                        // spread over 64 slices/image
    atomicMin(&slots[b * 64 + (sx & 63)],        __float_as_int(lmin));
    atomicMax(&slots[1024 + b * 64 + (sx & 63)], __float_as_int(lmax));
  }
  WBAR();
  float* T1 = WSf + T1BASE + (size_t)bc * T1SZ;
  const bool mir = (sx != 0) && (sx != 512);
#pragma unroll
  for (int obk = 0; obk < 4; ++obk) {
    int oh = l + 64 * obk;
    if (oh < OUTHW) {
      float x = ((float)oh + 0.5f) * KSCALE - 0.5f;
      int jlo = (int)ceilf(x - KSCALE);           // unclamped; window < 10 taps
      float ssum = 0.0f, acc = 0.0f, accm = 0.0f;
#pragma unroll
      for (int u = 0; u < 10; ++u) {
        int jj = jlo + u;
        float wgt = 1.0f - fabsf((float)jj - x) * SCALE;
        wgt = fmaxf(wgt, 0.0f);
        bool valid = (jj >= 0) && (jj <= N - 1);
        if (!valid) wgt = 0.0f;
        int ja = valid ? jj : 0;
        ssum += wgt;
        acc  += wgt * wb[ja];
        accm += wgt * wb[(N - ja) & (N - 1)];
      }
      float inv = 1.0f / ssum;
      T1[(size_t)sx * OUTHW + oh] = acc * inv;
      if (mir) T1[(size_t)(N - sx) * OUTHW + oh] = accm * inv;
    }
  }
}

// Pass 3 (R11-exact): contract v + normalization; direct coalesced T1 reads,
// fixed 10-tap unrolled loop, slot min/max reduction merged in.
__global__ __launch_bounds__(256) void k_resize2(const float* __restrict__ WSf,
                                                 const int* __restrict__ slots,
                                                 float* __restrict__ out) {
  __shared__ float s2[2];
  const int ow = blockIdx.x % OUTHW;
  const int bc = blockIdx.x / OUTHW;
  const int b  = bc / CH;
  const int t  = threadIdx.x;
  if (t < 64) {
    int mn = slots[b * 64 + t];
#pragma unroll
    for (int off = 32; off; off >>= 1) mn = min(mn, __shfl_xor(mn, off));
    if (t == 0) s2[0] = __int_as_float(mn);
  } else if (t < 128) {
    int mx = slots[1024 + b * 64 + (t - 64)];
#pragma unroll
    for (int off = 32; off; off >>= 1) mx = max(mx, __shfl_xor(mx, off));
    if (t == 64) s2[1] = __int_as_float(mx);
  }
  __syncthreads();
  if (t >= OUTHW) return;
  const float mn = s2[0];
  const float mx = s2[1];
  const float inv = 1.0f / (mx - mn + 1e-8f);
  const float* T1 = WSf + T1BASE + (size_t)bc * T1SZ;
  float x = ((float)ow + 0.5f) * KSCALE - 0.5f;
  int jlo = (int)ceilf(x - KSCALE);              // unclamped; window < 10 taps
  float ssum = 0.0f, acc = 0.0f;
#pragma unroll
  for (int u = 0; u < 10; ++u) {
    int jj = jlo + u;
    float wv = 1.0f - fabsf((float)jj - x) * SCALE;
    wv = fmaxf(wv, 0.0f);
    bool valid = (jj >= 0) && (jj <= N - 1);
    if (!valid) wv = 0.0f;
    int ja = valid ? jj : 0;                     // row 0 always valid memory
    ssum += wv;
    acc += wv * T1[(size_t)ja * OUTHW + t];      // coalesced 896B per tap row
  }
  float v = acc / ssum;
  out[((size_t)bc * OUTHW + t) * OUTHW + ow] = (v - mn) * inv;
}

extern "C" void kernel_launch(void* const* d_in, const int* in_sizes, int n_in,
                              void* d_out, int out_size, void* d_ws, size_t ws_size,
                              hipStream_t stream) {
  const float* in = (const float*)d_in[0];
  float* out = (float*)d_out;
  __half2* A = (__half2*)d_ws;                 // dense fp16 A region [0, 100.9MB)
  float* WSf = (float*)d_ws;
  int* slots = (int*)(WSf + SLOTBASE);         // [144.9MB, +8KB)

  k_init<<<8, 256, 0, stream>>>(slots);
  k_rowfft<<<BC * 64, 512, 0, stream>>>(in, A);
  k_colfft<<<(BC * 513) / 4, 256, 0, stream>>>(A, WSf, slots);
  k_resize2<<<BC * OUTHW, 256, 0, stream>>>(WSf, slots, out);
}